// Round 6
// baseline (4735.145 us; speedup 1.0000x reference)
//
#include <hip/hip_runtime.h>

typedef unsigned int uint;

enum { ACT_RELU=0, ACT_SIGMOID=1, ACT_RESBN=2 };

// ---------------- fused GEMM (f32): C = act(A @ W + bias) [+BN/residual] -----
// A:[M,K] row-major, W:[K,N] row-major. Optional second store C2 (same values).
// tile 64x64, BK=16, 256 threads, 4x4 acc/thread. M%64==0, K%16==0.
template<int ACT>
__global__ __launch_bounds__(256) void gemm_fused(
    const float* __restrict__ A, const float* __restrict__ W,
    const float* __restrict__ bias, float* __restrict__ C,
    float* __restrict__ C2, const float* __restrict__ R,
    const float* __restrict__ gamma, const float* __restrict__ beta,
    int M, int N, int K)
{
    __shared__ float As[16][68];
    __shared__ float Bs[16][68];
    const int tx = threadIdx.x, ty = threadIdx.y;
    const int tid = ty*16 + tx;
    const int row0 = blockIdx.y*64, col0 = blockIdx.x*64;
    float acc[4][4] = {};
    for (int k0 = 0; k0 < K; k0 += 16) {
        #pragma unroll
        for (int t = tid; t < 1024; t += 256) {
            int r = t >> 4, c = t & 15;
            As[c][r] = A[(size_t)(row0+r)*K + k0 + c];
        }
        #pragma unroll
        for (int t = tid; t < 1024; t += 256) {
            int kr = t >> 6, c = t & 63;
            int gc = col0 + c;
            Bs[kr][c] = (gc < N) ? W[(size_t)(k0+kr)*N + gc] : 0.f;
        }
        __syncthreads();
        #pragma unroll
        for (int kk = 0; kk < 16; kk++) {
            float a[4], b[4];
            #pragma unroll
            for (int i = 0; i < 4; i++) a[i] = As[kk][ty*4+i];
            #pragma unroll
            for (int j = 0; j < 4; j++) b[j] = Bs[kk][tx*4+j];
            #pragma unroll
            for (int i = 0; i < 4; i++)
                #pragma unroll
                for (int j = 0; j < 4; j++)
                    acc[i][j] += a[i]*b[j];
        }
        __syncthreads();
    }
    const float INVS = 0.99999500003749968f; // 1/sqrt(1+1e-5)
    #pragma unroll
    for (int i = 0; i < 4; i++) {
        int r = row0 + ty*4 + i;
        #pragma unroll
        for (int j = 0; j < 4; j++) {
            int c = col0 + tx*4 + j;
            if (c < N) {
                float v = acc[i][j] + bias[c];
                if (ACT == ACT_RELU) {
                    v = fmaxf(v, 0.f);
                } else if (ACT == ACT_SIGMOID) {
                    v = 1.f/(1.f + expf(-v));
                } else { // RESBN: relu -> *gamma/sqrt(1+eps)+beta -> +R
                    v = fmaxf(v, 0.f);
                    v = v*(gamma[c]*INVS) + beta[c];
                    v += R[(size_t)r*N + c];
                }
                C[(size_t)r*N + c] = v;
                if (C2) C2[(size_t)r*N + c] = v;
            }
        }
    }
}

// ---------------- split-K accumulating GEMM: C += A@W chunk ------------------
__global__ __launch_bounds__(256) void gemm_acc(
    const float* __restrict__ A, const float* __restrict__ W,
    float* __restrict__ C, int M, int N, int K, int kchunk)
{
    __shared__ float As[16][68];
    __shared__ float Bs[16][68];
    const int tx = threadIdx.x, ty = threadIdx.y;
    const int tid = ty*16 + tx;
    const int row0 = blockIdx.y*64, col0 = blockIdx.x*64;
    const int kbeg = blockIdx.z * kchunk, kend = kbeg + kchunk;
    float acc[4][4] = {};
    for (int k0 = kbeg; k0 < kend; k0 += 16) {
        #pragma unroll
        for (int t = tid; t < 1024; t += 256) {
            int r = t >> 4, c = t & 15;
            As[c][r] = A[(size_t)(row0+r)*K + k0 + c];
        }
        #pragma unroll
        for (int t = tid; t < 1024; t += 256) {
            int kr = t >> 6, c = t & 63;
            int gc = col0 + c;
            Bs[kr][c] = (gc < N) ? W[(size_t)(k0+kr)*N + gc] : 0.f;
        }
        __syncthreads();
        #pragma unroll
        for (int kk = 0; kk < 16; kk++) {
            float a[4], b[4];
            #pragma unroll
            for (int i = 0; i < 4; i++) a[i] = As[kk][ty*4+i];
            #pragma unroll
            for (int j = 0; j < 4; j++) b[j] = Bs[kk][tx*4+j];
            #pragma unroll
            for (int i = 0; i < 4; i++)
                #pragma unroll
                for (int j = 0; j < 4; j++)
                    acc[i][j] += a[i]*b[j];
        }
        __syncthreads();
    }
    #pragma unroll
    for (int i = 0; i < 4; i++) {
        int r = row0 + ty*4 + i;
        #pragma unroll
        for (int j = 0; j < 4; j++) {
            int c = col0 + tx*4 + j;
            if (c < N) atomicAdd(&C[(size_t)r*N + c], acc[i][j]);
        }
    }
}

// ---------------- epilogue for split-K results -------------------------------
template<int ACT>
__global__ __launch_bounds__(256) void epi_k(
    float* __restrict__ C, const float* __restrict__ bias,
    float* __restrict__ dst, int M, int N)
{
    int i = blockIdx.x*256 + threadIdx.x;
    if (i >= M*N) return;
    int c = i % N;
    float v = C[i] + bias[c];
    if (ACT == ACT_RELU) v = fmaxf(v, 0.f);
    else v = 1.f/(1.f + expf(-v));
    C[i] = v;
    if (dst) dst[i] = v;
}

__global__ __launch_bounds__(256) void zero_k(float* __restrict__ p, int n)
{
    int i = blockIdx.x*256 + threadIdx.x;
    if (i < n) p[i] = 0.f;
}

// ---------------- VQ: per-scalar transform -> argmin over 512 codes ----------
// one thread per (b,d). f32 codebook staged in LDS, 4 phases x 128 codes.
__global__ __launch_bounds__(256) void vq_k(
    const float* __restrict__ zencf, const float* __restrict__ Wt1,
    const float* __restrict__ bt1, const float* __restrict__ Wt2,
    const float* __restrict__ bt2, const float* __restrict__ E,
    float* __restrict__ qout, float* __restrict__ sumsq, float* __restrict__ counts)
{
    __shared__ __align__(16) float Es[8192];    // 128 codes x 64 f32 = 32KB
    __shared__ float Esq[128];
    __shared__ __align__(16) float Wt2s[2048];  // 32x64
    __shared__ float Wt1s[32], bt1s[32], bt2s[64];
    __shared__ float red[256];
    const int tid = threadIdx.x;

    for (int t = tid; t < 2048; t += 256) Wt2s[t] = Wt2[t];
    if (tid < 32) { Wt1s[tid] = Wt1[tid]; bt1s[tid] = bt1[tid]; }
    if (tid < 64) bt2s[tid] = bt2[tid];
    __syncthreads();

    const int gid = blockIdx.x*256 + tid;
    const float z = zencf[gid];
    float e[64];
    #pragma unroll
    for (int j = 0; j < 64; j++) e[j] = bt2s[j];
    #pragma unroll
    for (int i = 0; i < 32; i++) {
        float a = fmaxf(z*Wt1s[i] + bt1s[i], 0.f);
        #pragma unroll
        for (int j4 = 0; j4 < 16; j4++) {
            float4 w = ((const float4*)Wt2s)[i*16 + j4];
            e[j4*4+0] += a*w.x; e[j4*4+1] += a*w.y;
            e[j4*4+2] += a*w.z; e[j4*4+3] += a*w.w;
        }
    }

    float best = 3.4e38f; int bi = 0;
    for (int ph = 0; ph < 4; ph++) {
        __syncthreads();
        const float4* Eg = (const float4*)(E + ph*8192);   // 128 codes x 64 f32
        for (int t = tid; t < 2048; t += 256) ((float4*)Es)[t] = Eg[t];
        __syncthreads();
        if (tid < 128) {
            const float4* row = (const float4*)(Es + tid*64);
            float s = 0.f;
            #pragma unroll
            for (int m = 0; m < 16; m++) {
                float4 w = row[m];
                s += w.x*w.x + w.y*w.y + w.z*w.z + w.w*w.w;
            }
            Esq[tid] = s;
        }
        __syncthreads();
        for (int k = 0; k < 128; k++) {
            const float4* row = (const float4*)(Es + k*64);
            float d0=0.f, d1=0.f, d2=0.f, d3=0.f;
            #pragma unroll
            for (int m = 0; m < 16; m++) {
                float4 w = row[m];
                d0 += e[4*m+0]*w.x; d1 += e[4*m+1]*w.y;
                d2 += e[4*m+2]*w.z; d3 += e[4*m+3]*w.w;
            }
            float s = Esq[k] - 2.f*((d0+d1)+(d2+d3));
            if (s < best) { best = s; bi = ph*128 + k; }  // first-min like np.argmin
        }
    }

    // q = E[bi] exact f32 copy; local (q-e)^2 sum; histogram
    float ls = 0.f;
    float* qo = qout + (size_t)gid*64;
    const float* Eq = E + (size_t)bi*64;
    #pragma unroll
    for (int j = 0; j < 64; j++) {
        float w = Eq[j];
        qo[j] = w;
        float d = w - e[j];
        ls += d*d;
    }
    atomicAdd(&counts[bi], 1.f);
    red[tid] = ls; __syncthreads();
    for (int s = 128; s > 0; s >>= 1) { if (tid < s) red[tid] += red[tid+s]; __syncthreads(); }
    if (tid == 0) atomicAdd(sumsq, red[0]);
}

// ---------------- losses / perplexity ---------------------------------------
__global__ __launch_bounds__(512) void finalize_k(
    const float* __restrict__ sumsq, const float* __restrict__ counts,
    float* __restrict__ out)
{
    __shared__ float red[512];
    int tid = threadIdx.x;
    float p = counts[tid] * (1.f/262144.f);
    red[tid] = p * logf(p + 1e-10f);
    __syncthreads();
    for (int s = 256; s > 0; s >>= 1) { if (tid < s) red[tid] += red[tid+s]; __syncthreads(); }
    if (tid == 0) {
        out[0]       = 1.25f * sumsq[0] * (1.f/16777216.f); // vq_loss = (1+0.25)*mse
        out[2097153] = expf(-red[0]);                        // perplexity
    }
}

extern "C" void kernel_launch(void* const* d_in, const int* in_sizes, int n_in,
                              void* d_out, int out_size, void* d_ws, size_t ws_size,
                              hipStream_t stream)
{
    // Reference dtypes are float32 throughout -> all inputs/outputs are f32.
    const float* x    = (const float*)d_in[0];
    const float* We1  = (const float*)d_in[1];  const float* be1  = (const float*)d_in[2];
    const float* We2  = (const float*)d_in[3];  const float* be2  = (const float*)d_in[4];
    const float* Wre1 = (const float*)d_in[5];  const float* bre1 = (const float*)d_in[6];
    const float* Wre2 = (const float*)d_in[7];  const float* bre2 = (const float*)d_in[8];
    const float* ge   = (const float*)d_in[9];  const float* bebn = (const float*)d_in[10];
    const float* E    = (const float*)d_in[11];
    const float* Wt1  = (const float*)d_in[12]; const float* bt1  = (const float*)d_in[13];
    const float* Wt2  = (const float*)d_in[14]; const float* bt2  = (const float*)d_in[15];
    const float* Wc   = (const float*)d_in[16]; const float* bc   = (const float*)d_in[17];
    const float* Wp   = (const float*)d_in[18]; const float* bp   = (const float*)d_in[19];
    const float* Wrd1 = (const float*)d_in[20]; const float* brd1 = (const float*)d_in[21];
    const float* Wrd2 = (const float*)d_in[22]; const float* brd2 = (const float*)d_in[23];
    const float* gd   = (const float*)d_in[24]; const float* bdbn = (const float*)d_in[25];
    const float* Wd1  = (const float*)d_in[26]; const float* bd1  = (const float*)d_in[27];
    const float* Wd2  = (const float*)d_in[28]; const float* bd2  = (const float*)d_in[29];

    // f32 output, flat: vq_loss[1] | x_recon[2097152] | ppl[1] | q_st[16777216]
    //                  | cls[5120] | zenc[262144]
    float* out    = (float*)d_out;
    float* o_xr   = out + 1;
    float* o_q    = out + 2097154;
    float* o_cls  = out + 18874370;
    float* o_zenc = out + 18879490;

    // ws (floats): small zeroed buffers first; total ~8.5 MB.
    float* ws    = (float*)d_ws;
    float* sumsq = ws + 0;        // 1      [zeroed]
    float* cnts  = ws + 16;       // 512    [zeroed]
    float* t1    = ws + 528;      // 8192   [zeroed]
    float* t2    = ws + 8720;     // 8192   [zeroed]
    float* clsf  = ws + 16912;    // 5120   [zeroed]
    float* z0    = ws + 22032;    // 262144 [zeroed]
    float* dp0   = ws + 284176;   // 262144 [zeroed]
    float* zencf = ws + 546320;   // 262144
    float* dd    = ws + 808464;   // 262144
    float* hbuf  = ws + 1070608;  // 1048576 (dead before d2 -> d2 reuses)
    float* d2    = ws + 1070608;

    dim3 blk(16, 16);

    zero_k<<<dim3(2135), dim3(256), 0, stream>>>(ws, 546320);

    // ---- encoder ----
    gemm_fused<ACT_RELU><<<dim3(32, 8), blk, 0, stream>>>(
        x, We1, be1, hbuf, nullptr, nullptr, nullptr, nullptr, 512, 2048, 4096);
    gemm_acc<<<dim3(8, 8, 4), blk, 0, stream>>>(hbuf, We2, z0, 512, 512, 2048, 512);
    epi_k<ACT_RELU><<<dim3(1024), dim3(256), 0, stream>>>(z0, be2, nullptr, 512, 512);
    gemm_acc<<<dim3(1, 8, 32), blk, 0, stream>>>(z0, Wre1, t1, 512, 16, 512, 16);
    epi_k<ACT_RELU><<<dim3(32), dim3(256), 0, stream>>>(t1, bre1, nullptr, 512, 16);
    gemm_fused<ACT_RESBN><<<dim3(8, 8), blk, 0, stream>>>(
        t1, Wre2, bre2, zencf, o_zenc, z0, ge, bebn, 512, 512, 16);

    // ---- vector quantizer ----
    vq_k<<<dim3(1024), dim3(256), 0, stream>>>(zencf, Wt1, bt1, Wt2, bt2, E,
                                               o_q, sumsq, cnts);
    finalize_k<<<dim3(1), dim3(512), 0, stream>>>(sumsq, cnts, out);

    // ---- classifier head ----
    gemm_acc<<<dim3(1, 8, 32), blk, 0, stream>>>(o_q, Wc, clsf, 512, 10, 32768, 1024);
    epi_k<ACT_SIGMOID><<<dim3(20), dim3(256), 0, stream>>>(clsf, bc, o_cls, 512, 10);

    // ---- decoder ----
    gemm_acc<<<dim3(8, 8, 8), blk, 0, stream>>>(o_q, Wp, dp0, 512, 512, 32768, 4096);
    epi_k<ACT_RELU><<<dim3(1024), dim3(256), 0, stream>>>(dp0, bp, nullptr, 512, 512);
    gemm_acc<<<dim3(1, 8, 32), blk, 0, stream>>>(dp0, Wrd1, t2, 512, 16, 512, 16);
    epi_k<ACT_RELU><<<dim3(32), dim3(256), 0, stream>>>(t2, brd1, nullptr, 512, 16);
    gemm_fused<ACT_RESBN><<<dim3(8, 8), blk, 0, stream>>>(
        t2, Wrd2, brd2, dd, nullptr, dp0, gd, bdbn, 512, 512, 16);
    gemm_fused<ACT_RELU><<<dim3(32, 8), blk, 0, stream>>>(
        dd, Wd1, bd1, d2, nullptr, nullptr, nullptr, nullptr, 512, 2048, 512);
    gemm_fused<ACT_RELU><<<dim3(64, 8), blk, 0, stream>>>(
        d2, Wd2, bd2, o_xr, nullptr, nullptr, nullptr, nullptr, 512, 4096, 2048);
}